// Round 7
// baseline (37977.399 us; speedup 1.0000x reference)
//
#include <hip/hip_runtime.h>

#define D_IN   2048
#define WIDTH  16384
#define BATCH  8192
#define TOPK   64
#define RPB    32
#define TCOLS  64
#define TK     32
#define CAP    320
#define BAND   0.02f

typedef unsigned int u32;

// Two disjoint execution phases share one LDS allocation (~13.8 KB).
struct SmemA {                      // phase A: GEMM tiles
  float Wt[TCOLS][36];              // 9216 B
  float xs[RPB][36];                // 4608 B
};
struct SmemB {                      // phase B: top-k select + decode
  float  xrow[D_IN];                // 8192 B
  u32    hist[256];                 // 1024 B
  int    ci[CAP];                   // 1280 B
  double cv[CAP];                   // 2560 B
  int    si[TOPK];                  //  256 B
  float  sv[TOPK];                  //  256 B
};
union SmemU { SmemA a; SmemB b; };

// One block owns 32 batch rows end-to-end; ONE launch for the whole problem.
// ALL outputs are float32 (the reference's dtype).
__global__ __launch_bounds__(256) void BaseSAE_35622458753216_kernel(
    const float* __restrict__ x, const float* __restrict__ W,
    const float* __restrict__ b_enc, const float* __restrict__ b_dec,
    float* __restrict__ z, float* __restrict__ xhat)
{
  __shared__ SmemU sm;
  __shared__ int   ncand_s;
  __shared__ int   sel_hi_s;
  __shared__ u32   g1_s;
  __shared__ float tf_s;

  const int tid = threadIdx.x;
  const int b0  = blockIdx.x * RPB;
  const int rr  = tid & 15;          // rows 2rr, 2rr+1
  const int g   = tid >> 4;          // 0..15 -> cols g*4 .. g*4+3

  // ============ Phase A: z = relu(x @ W^T + b_enc), dense f32 staging ============
  for (int bn = 0; bn < WIDTH / TCOLS; bn++) {
    float acc0[4], acc1[4];
    for (int cc = 0; cc < 4; cc++) { acc0[cc] = 0.f; acc1[cc] = 0.f; }

    for (int k0 = 0; k0 < D_IN; k0 += TK) {
      __syncthreads();
      {
        int j = tid >> 2, q = tid & 3;                        // W tile: col j, octet q
        const float* wsrc = W + (size_t)(bn * TCOLS + j) * D_IN + k0 + q * 8;
        float4 w0 = *(const float4*)(wsrc);
        float4 w1 = *(const float4*)(wsrc + 4);
        *(float4*)&sm.a.Wt[j][q * 8]     = w0;
        *(float4*)&sm.a.Wt[j][q * 8 + 4] = w1;
        int r = tid >> 3, p = tid & 7;                        // x tile: row r, quad p
        float4 xv = *(const float4*)(x + (size_t)(b0 + r) * D_IN + k0 + p * 4);
        *(float4*)&sm.a.xs[r][p * 4] = xv;
      }
      __syncthreads();
      for (int kk = 0; kk < TK; kk += 4) {
        float4 a0 = *(const float4*)&sm.a.xs[2 * rr][kk];
        float4 a1 = *(const float4*)&sm.a.xs[2 * rr + 1][kk];
        for (int cc = 0; cc < 4; cc++) {
          float4 wv = *(const float4*)&sm.a.Wt[g * 4 + cc][kk];
          acc0[cc] = fmaf(a0.x, wv.x, acc0[cc]);
          acc0[cc] = fmaf(a0.y, wv.y, acc0[cc]);
          acc0[cc] = fmaf(a0.z, wv.z, acc0[cc]);
          acc0[cc] = fmaf(a0.w, wv.w, acc0[cc]);
          acc1[cc] = fmaf(a1.x, wv.x, acc1[cc]);
          acc1[cc] = fmaf(a1.y, wv.y, acc1[cc]);
          acc1[cc] = fmaf(a1.z, wv.z, acc1[cc]);
          acc1[cc] = fmaf(a1.w, wv.w, acc1[cc]);
        }
      }
    }
    // coalesced float4 epilogue: bias + relu
    float4 o0, o1;
    {
      int c = bn * TCOLS + g * 4;
      float4 be = *(const float4*)(b_enc + c);
      o0.x = fmaxf(acc0[0] + be.x, 0.f); o0.y = fmaxf(acc0[1] + be.y, 0.f);
      o0.z = fmaxf(acc0[2] + be.z, 0.f); o0.w = fmaxf(acc0[3] + be.w, 0.f);
      o1.x = fmaxf(acc1[0] + be.x, 0.f); o1.y = fmaxf(acc1[1] + be.y, 0.f);
      o1.z = fmaxf(acc1[2] + be.z, 0.f); o1.w = fmaxf(acc1[3] + be.w, 0.f);
      *(float4*)(z + (size_t)(b0 + 2 * rr) * WIDTH + c)     = o0;
      *(float4*)(z + (size_t)(b0 + 2 * rr + 1) * WIDTH + c) = o1;
    }
  }
  __threadfence();
  __syncthreads();

  // ===== Phase B: per-row exact top-64, sparsify z in place, fused decode =====
  for (int r = 0; r < RPB; r++) {
    int b = b0 + r;
    float* zrow = z + (size_t)b * WIDTH;

    for (int i = tid; i < D_IN / 4; i += 256)
      *(float4*)&sm.b.xrow[i * 4] = *(const float4*)(x + (size_t)b * D_IN + i * 4);
    if (tid == 0) ncand_s = 0;
    if (tid < TOPK) { sm.b.si[tid] = 0; sm.b.sv[tid] = 0.f; }
    sm.b.hist[tid] = 0;
    __syncthreads();

    // radix pass 1 on f32 bits (nonneg -> order-preserving): bits[31:24]
    for (int j = tid; j < WIDTH; j += 256) {
      u32 k = __float_as_uint(zrow[j]);
      atomicAdd(&sm.b.hist[k >> 24], 1u);
    }
    __syncthreads();
    if (tid == 0) {
      u32 cum = 0; int hi = 255;
      for (; hi > 0; hi--) { if (cum + sm.b.hist[hi] >= TOPK) break; cum += sm.b.hist[hi]; }
      sel_hi_s = hi; g1_s = cum;
    }
    __syncthreads();
    int sel_hi = sel_hi_s;
    sm.b.hist[tid] = 0;
    __syncthreads();
    // radix pass 2: bits[23:16] within the boundary high-bin
    for (int j = tid; j < WIDTH; j += 256) {
      u32 k = __float_as_uint(zrow[j]);
      if ((int)(k >> 24) == sel_hi) atomicAdd(&sm.b.hist[(k >> 16) & 255u], 1u);
    }
    __syncthreads();
    if (tid == 0) {
      u32 target = TOPK - g1_s;
      u32 cum = 0; int lo = 255;
      for (; lo > 0; lo--) { cum += sm.b.hist[lo]; if (cum >= target) break; }
      u32 t16 = ((u32)sel_hi << 8) | (u32)lo;
      tf_s = __uint_as_float(t16 << 16);   // truncated 64th-largest staged value
    }
    __syncthreads();

    // candidate band: covers 16-bit truncation (<=0.016) + f32 GEMM noise
    float thresh = tf_s - BAND;
    for (int j = tid; j < WIDTH; j += 256) {
      if (zrow[j] >= thresh) {
        int p = atomicAdd(&ncand_s, 1);
        if (p < CAP) sm.b.ci[p] = j;
      }
    }
    __syncthreads();
    int nc = ncand_s; if (nc > CAP) nc = CAP;

    // f64-exact recompute of candidates: one wave per candidate, coalesced W reads
    int wid = tid >> 6, lane = tid & 63;
    for (int c = wid; c < nc; c += 4) {
      int jc = sm.b.ci[c];
      const float4* wr = (const float4*)(W + (size_t)jc * D_IN);
      double s = 0.0;
      for (int it = 0; it < D_IN / 4 / 64; it++) {
        float4 w = wr[it * 64 + lane];
        int d = (it * 64 + lane) * 4;
        s += (double)sm.b.xrow[d + 0] * (double)w.x;
        s += (double)sm.b.xrow[d + 1] * (double)w.y;
        s += (double)sm.b.xrow[d + 2] * (double)w.z;
        s += (double)sm.b.xrow[d + 3] * (double)w.w;
      }
      for (int off = 32; off >= 1; off >>= 1) s += __shfl_down(s, off, 64);
      if (lane == 0) sm.b.cv[c] = s + (double)b_enc[jc];
    }
    __syncthreads();

    // exact ranking: descending value, lower index wins ties (matches lax.top_k)
    for (int t = tid; t < nc; t += 256) {
      double v = sm.b.cv[t]; int jt = sm.b.ci[t];
      int rank = 0;
      for (int c = 0; c < nc; c++) {
        double vc = sm.b.cv[c];
        if (vc > v || (vc == v && sm.b.ci[c] < jt)) rank++;
      }
      if (rank < TOPK) {
        float fv = (float)v; if (fv < 0.f) fv = 0.f;
        sm.b.si[rank] = jt;
        sm.b.sv[rank] = fv;
      }
    }
    __syncthreads();

    // zero the row, then scatter the 64 winners (f32)
    for (int i = tid; i < WIDTH / 4; i += 256)
      *(float4*)(zrow + i * 4) = make_float4(0.f, 0.f, 0.f, 0.f);
    __syncthreads();
    if (tid < TOPK) zrow[sm.b.si[tid]] = sm.b.sv[tid];

    // decode: x_hat[b] = sum_k val_k * W[idx_k, :] + b_dec   (f32)
    float d0 = 0.f, d1 = 0.f, d2 = 0.f, d3 = 0.f;
    float d4 = 0.f, d5 = 0.f, d6 = 0.f, d7 = 0.f;
    for (int k = 0; k < TOPK; k++) {
      int jk = sm.b.si[k]; float v = sm.b.sv[k];
      const float* wr = W + (size_t)jk * D_IN;
      d0 = fmaf(v, wr[tid],        d0);
      d1 = fmaf(v, wr[tid +  256], d1);
      d2 = fmaf(v, wr[tid +  512], d2);
      d3 = fmaf(v, wr[tid +  768], d3);
      d4 = fmaf(v, wr[tid + 1024], d4);
      d5 = fmaf(v, wr[tid + 1280], d5);
      d6 = fmaf(v, wr[tid + 1536], d6);
      d7 = fmaf(v, wr[tid + 1792], d7);
    }
    float* xo = xhat + (size_t)b * D_IN;
    xo[tid]        = d0 + b_dec[tid];
    xo[tid +  256] = d1 + b_dec[tid +  256];
    xo[tid +  512] = d2 + b_dec[tid +  512];
    xo[tid +  768] = d3 + b_dec[tid +  768];
    xo[tid + 1024] = d4 + b_dec[tid + 1024];
    xo[tid + 1280] = d5 + b_dec[tid + 1280];
    xo[tid + 1536] = d6 + b_dec[tid + 1536];
    xo[tid + 1792] = d7 + b_dec[tid + 1792];
    __syncthreads();
  }
}

extern "C" void kernel_launch(void* const* d_in, const int* in_sizes, int n_in,
                              void* d_out, int out_size, void* d_ws, size_t ws_size,
                              hipStream_t stream) {
  const float* x     = (const float*)d_in[0];
  const float* W     = (const float*)d_in[1];
  const float* b_enc = (const float*)d_in[2];
  const float* b_dec = (const float*)d_in[3];
  (void)in_sizes; (void)n_in; (void)out_size; (void)d_ws; (void)ws_size;

  float* z_out = (float*)d_out;                      // [BATCH][WIDTH] f32
  float* xhat  = z_out + (size_t)BATCH * WIDTH;      // [BATCH][D_IN] f32

  BaseSAE_35622458753216_kernel<<<BATCH / RPB, 256, 0, stream>>>(
      x, W, b_enc, b_dec, z_out, xhat);
}

// Round 8
// 3355.640 us; speedup vs baseline: 11.3175x; 11.3175x over previous
//
#include <hip/hip_runtime.h>

#define D_IN   2048
#define WIDTH  16384
#define BATCH  8192
#define TOPK   64

// ---- K1 (MFMA GEMM) tiles ----
#define BM  128
#define BN  128
#define BK  64
#define LDB 72            // LDS row stride in bf16 elems (144 B) -> breaks 128B-stride conflicts

// ---- K2 (select) ----
#define CAP  320
#define BAND 0.08f

typedef unsigned int   u32;
typedef unsigned short u16;
typedef __attribute__((ext_vector_type(8))) short short8;
typedef __attribute__((ext_vector_type(4))) float f32x4;

// =================== K1: z = relu(x @ W^T + b_enc), bf16 MFMA ===================
__global__ __launch_bounds__(256) void sae_enc_mfma(
    const float* __restrict__ x, const float* __restrict__ W,
    const float* __restrict__ b_enc, float* __restrict__ z)
{
  __shared__ u16 lds[2 * BM * LDB];            // As | Bs, 36864 B
  u16* As = lds;
  u16* Bs = lds + BM * LDB;

  const int tid  = threadIdx.x;
  const int lane = tid & 63;
  const int wid  = tid >> 6;
  const int wm   = wid >> 1;                   // 0..1 : wave row
  const int wn   = wid & 1;                    // 0..1 : wave col
  const int bn   = blockIdx.x;                 // 0..127
  const int bm   = blockIdx.y;                 // 0..63

  f32x4 acc[4][4];
#pragma unroll
  for (int i = 0; i < 4; i++)
#pragma unroll
    for (int j = 0; j < 4; j++) acc[i][j] = (f32x4){0.f, 0.f, 0.f, 0.f};

  const float* xg = x + (size_t)(bm * BM) * D_IN;
  const float* wg = W + (size_t)(bn * BN) * D_IN;

  for (int k0 = 0; k0 < D_IN; k0 += BK) {
    __syncthreads();
    // stage both tiles: 128 rows x 16 float4 each; f32 -> bf16 by truncation
    // (selection band + f64 recompute absorb the rounding; values rewritten exactly later)
#pragma unroll
    for (int i = 0; i < 8; i++) {
      int f4  = i * 256 + tid;
      int row = f4 >> 4;
      int k4  = f4 & 15;
      float4 va = *(const float4*)(xg + (size_t)row * D_IN + k0 + k4 * 4);
      u32 a0 = (__float_as_uint(va.x) >> 16) | (__float_as_uint(va.y) & 0xFFFF0000u);
      u32 a1 = (__float_as_uint(va.z) >> 16) | (__float_as_uint(va.w) & 0xFFFF0000u);
      *(uint2*)&As[row * LDB + k4 * 4] = make_uint2(a0, a1);
      float4 vb = *(const float4*)(wg + (size_t)row * D_IN + k0 + k4 * 4);
      u32 b0 = (__float_as_uint(vb.x) >> 16) | (__float_as_uint(vb.y) & 0xFFFF0000u);
      u32 b1 = (__float_as_uint(vb.z) >> 16) | (__float_as_uint(vb.w) & 0xFFFF0000u);
      *(uint2*)&Bs[row * LDB + k4 * 4] = make_uint2(b0, b1);
    }
    __syncthreads();
#pragma unroll
    for (int kf = 0; kf < 2; kf++) {
      int ko = kf * 32 + (lane >> 4) * 8;      // lane's 8 consecutive k
      short8 af[4], bf[4];
#pragma unroll
      for (int mi = 0; mi < 4; mi++)
        af[mi] = *(const short8*)&As[(wm * 64 + mi * 16 + (lane & 15)) * LDB + ko];
#pragma unroll
      for (int ni = 0; ni < 4; ni++)
        bf[ni] = *(const short8*)&Bs[(wn * 64 + ni * 16 + (lane & 15)) * LDB + ko];
#pragma unroll
      for (int mi = 0; mi < 4; mi++)
#pragma unroll
        for (int ni = 0; ni < 4; ni++)
          acc[mi][ni] = __builtin_amdgcn_mfma_f32_16x16x32_bf16(
              af[mi], bf[ni], acc[mi][ni], 0, 0, 0);
    }
  }

  // epilogue: C layout col = lane&15, row = (lane>>4)*4 + reg   [m89-verified]
  int colbase = bn * BN + wn * 64 + (lane & 15);
  int rowbase = bm * BM + wm * 64 + (lane >> 4) * 4;
#pragma unroll
  for (int ni = 0; ni < 4; ni++) {
    int col = colbase + ni * 16;
    float be = b_enc[col];
#pragma unroll
    for (int mi = 0; mi < 4; mi++) {
#pragma unroll
      for (int r = 0; r < 4; r++) {
        int row = rowbase + mi * 16 + r;
        float v = acc[mi][ni][r] + be;
        z[(size_t)row * WIDTH + col] = v > 0.f ? v : 0.f;
      }
    }
  }
}

// ========= K2: per-row exact top-64, sparsify z in place, fused decode =========
__global__ __launch_bounds__(256) void sae_topk_decode(
    float* __restrict__ z, const float* __restrict__ x,
    const float* __restrict__ W, const float* __restrict__ b_enc,
    const float* __restrict__ b_dec, float* __restrict__ xhat)
{
  __shared__ float  xrow[D_IN];        // 8192 B
  __shared__ u32    hist[256];         // 1024 B
  __shared__ int    ci[CAP];           // 1280 B
  __shared__ double cv[CAP];           // 2560 B
  __shared__ int    si[TOPK];          //  256 B
  __shared__ float  sv[TOPK];          //  256 B
  __shared__ int    ncand_s;
  __shared__ int    sel_hi_s;
  __shared__ u32    g1_s;
  __shared__ float  tf_s;

  const int tid = threadIdx.x;
  const int b   = blockIdx.x;
  float* zrow = z + (size_t)b * WIDTH;

  for (int i = tid; i < D_IN / 4; i += 256)
    *(float4*)&xrow[i * 4] = *(const float4*)(x + (size_t)b * D_IN + i * 4);
  if (tid == 0) ncand_s = 0;
  if (tid < TOPK) { si[tid] = 0; sv[tid] = 0.f; }
  hist[tid] = 0;
  __syncthreads();

  // radix pass 1 on f32 bits (nonneg -> order-preserving): bits[31:24]
  for (int j = tid; j < WIDTH; j += 256) {
    u32 k = __float_as_uint(zrow[j]);
    atomicAdd(&hist[k >> 24], 1u);
  }
  __syncthreads();
  if (tid == 0) {
    u32 cum = 0; int hi = 255;
    for (; hi > 0; hi--) { if (cum + hist[hi] >= TOPK) break; cum += hist[hi]; }
    sel_hi_s = hi; g1_s = cum;
  }
  __syncthreads();
  int sel_hi = sel_hi_s;
  hist[tid] = 0;
  __syncthreads();
  // radix pass 2: bits[23:16] within the boundary high-bin
  for (int j = tid; j < WIDTH; j += 256) {
    u32 k = __float_as_uint(zrow[j]);
    if ((int)(k >> 24) == sel_hi) atomicAdd(&hist[(k >> 16) & 255u], 1u);
  }
  __syncthreads();
  if (tid == 0) {
    u32 target = TOPK - g1_s;
    u32 cum = 0; int lo = 255;
    for (; lo > 0; lo--) { cum += hist[lo]; if (cum >= target) break; }
    u32 t16 = ((u32)sel_hi << 8) | (u32)lo;
    tf_s = __uint_as_float(t16 << 16);   // truncated 64th-largest staged value
  }
  __syncthreads();

  // candidate band: covers bf16 GEMM error + 16-bit truncation with margin
  float thresh = tf_s - BAND;
  for (int j = tid; j < WIDTH; j += 256) {
    if (zrow[j] >= thresh) {
      int p = atomicAdd(&ncand_s, 1);
      if (p < CAP) ci[p] = j;
    }
  }
  __syncthreads();
  int nc = ncand_s; if (nc > CAP) nc = CAP;

  // f64-exact recompute: one wave per candidate, coalesced W reads
  int wid = tid >> 6, lane = tid & 63;
  for (int c = wid; c < nc; c += 4) {
    int jc = ci[c];
    const float4* wr = (const float4*)(W + (size_t)jc * D_IN);
    double s = 0.0;
    for (int it = 0; it < D_IN / 4 / 64; it++) {
      float4 w = wr[it * 64 + lane];
      int d = (it * 64 + lane) * 4;
      s += (double)xrow[d + 0] * (double)w.x;
      s += (double)xrow[d + 1] * (double)w.y;
      s += (double)xrow[d + 2] * (double)w.z;
      s += (double)xrow[d + 3] * (double)w.w;
    }
    for (int off = 32; off >= 1; off >>= 1) s += __shfl_down(s, off, 64);
    if (lane == 0) cv[c] = s + (double)b_enc[jc];
  }
  __syncthreads();

  // exact ranking: descending value, lower index wins ties (matches lax.top_k)
  for (int t = tid; t < nc; t += 256) {
    double v = cv[t]; int jt = ci[t];
    int rank = 0;
    for (int c = 0; c < nc; c++) {
      double vc = cv[c];
      if (vc > v || (vc == v && ci[c] < jt)) rank++;
    }
    if (rank < TOPK) {
      float fv = (float)v; if (fv < 0.f) fv = 0.f;
      si[rank] = jt;
      sv[rank] = fv;
    }
  }
  __syncthreads();

  // zero the row, then scatter the 64 winners
  for (int i = tid; i < WIDTH / 4; i += 256)
    *(float4*)(zrow + i * 4) = make_float4(0.f, 0.f, 0.f, 0.f);
  __syncthreads();
  if (tid < TOPK) zrow[si[tid]] = sv[tid];

  // decode: x_hat[b] = sum_k val_k * W[idx_k, :] + b_dec
  float d0 = 0.f, d1 = 0.f, d2 = 0.f, d3 = 0.f;
  float d4 = 0.f, d5 = 0.f, d6 = 0.f, d7 = 0.f;
  for (int k = 0; k < TOPK; k++) {
    int jk = si[k]; float v = sv[k];
    const float* wr = W + (size_t)jk * D_IN;
    d0 = fmaf(v, wr[tid],        d0);
    d1 = fmaf(v, wr[tid +  256], d1);
    d2 = fmaf(v, wr[tid +  512], d2);
    d3 = fmaf(v, wr[tid +  768], d3);
    d4 = fmaf(v, wr[tid + 1024], d4);
    d5 = fmaf(v, wr[tid + 1280], d5);
    d6 = fmaf(v, wr[tid + 1536], d6);
    d7 = fmaf(v, wr[tid + 1792], d7);
  }
  float* xo = xhat + (size_t)b * D_IN;
  xo[tid]        = d0 + b_dec[tid];
  xo[tid +  256] = d1 + b_dec[tid +  256];
  xo[tid +  512] = d2 + b_dec[tid +  512];
  xo[tid +  768] = d3 + b_dec[tid +  768];
  xo[tid + 1024] = d4 + b_dec[tid + 1024];
  xo[tid + 1280] = d5 + b_dec[tid + 1280];
  xo[tid + 1536] = d6 + b_dec[tid + 1536];
  xo[tid + 1792] = d7 + b_dec[tid + 1792];
}

// ------------------------------- launch -------------------------------
extern "C" void kernel_launch(void* const* d_in, const int* in_sizes, int n_in,
                              void* d_out, int out_size, void* d_ws, size_t ws_size,
                              hipStream_t stream) {
  const float* x     = (const float*)d_in[0];
  const float* W     = (const float*)d_in[1];
  const float* b_enc = (const float*)d_in[2];
  const float* b_dec = (const float*)d_in[3];
  (void)in_sizes; (void)n_in; (void)out_size; (void)d_ws; (void)ws_size;

  float* z_out = (float*)d_out;                      // [BATCH][WIDTH] f32
  float* xhat  = z_out + (size_t)BATCH * WIDTH;      // [BATCH][D_IN] f32

  dim3 g1(WIDTH / BN, BATCH / BM);                   // 128 x 64
  sae_enc_mfma<<<g1, 256, 0, stream>>>(x, W, b_enc, z_out);
  sae_topk_decode<<<BATCH, 256, 0, stream>>>(z_out, x, W, b_enc, b_dec, xhat);
}

// Round 9
// 2754.905 us; speedup vs baseline: 13.7854x; 1.2181x over previous
//
#include <hip/hip_runtime.h>

#define D_IN   2048
#define WIDTH  16384
#define BATCH  8192
#define TOPK   64

// ---- K1 (MFMA GEMM) ----
#define BM  128
#define BN  128
#define BK  64
#define LDB 72            // LDS row stride in bf16 elems (144 B)

// ---- K2a (select) ----
#define CAP   256
#define COLL  0.022f      // collect band on bf16-staged s'
#define SURE  0.018f      // certainty band on f32-staged s

typedef unsigned int   u32;
typedef unsigned short u16;
typedef __attribute__((ext_vector_type(8))) short short8;
typedef __attribute__((ext_vector_type(4))) float f32x4;

__device__ __forceinline__ u32 rne16(float f) {           // f32 -> bf16 bits (RNE)
  u32 u = __float_as_uint(f);
  return (u + 0x7FFFu + ((u >> 16) & 1u)) >> 16;
}
__device__ __forceinline__ float bf16f(u16 h) {
  return __uint_as_float(((u32)h) << 16);
}

// =================== K1: z = relu(x @ W^T + b_enc), bf16 MFMA ===================
__global__ __launch_bounds__(256) void sae_enc_mfma(
    const float* __restrict__ x, const float* __restrict__ W,
    const float* __restrict__ b_enc, float* __restrict__ z)
{
  __shared__ u16 lds[2 * BM * LDB];
  u16* As = lds;
  u16* Bs = lds + BM * LDB;

  const int tid  = threadIdx.x;
  const int lane = tid & 63;
  const int wid  = tid >> 6;
  const int wm   = wid >> 1;
  const int wn   = wid & 1;
  const int bn   = blockIdx.x;
  const int bm   = blockIdx.y;

  f32x4 acc[4][4];
#pragma unroll
  for (int i = 0; i < 4; i++)
#pragma unroll
    for (int j = 0; j < 4; j++) acc[i][j] = (f32x4){0.f, 0.f, 0.f, 0.f};

  const float* xg = x + (size_t)(bm * BM) * D_IN;
  const float* wg = W + (size_t)(bn * BN) * D_IN;

  for (int k0 = 0; k0 < D_IN; k0 += BK) {
    __syncthreads();
#pragma unroll
    for (int i = 0; i < 8; i++) {
      int f4  = i * 256 + tid;
      int row = f4 >> 4;
      int k4  = f4 & 15;
      float4 va = *(const float4*)(xg + (size_t)row * D_IN + k0 + k4 * 4);
      u32 a0 = rne16(va.x) | (rne16(va.y) << 16);
      u32 a1 = rne16(va.z) | (rne16(va.w) << 16);
      *(uint2*)&As[row * LDB + k4 * 4] = make_uint2(a0, a1);
      float4 vb = *(const float4*)(wg + (size_t)row * D_IN + k0 + k4 * 4);
      u32 b0 = rne16(vb.x) | (rne16(vb.y) << 16);
      u32 b1 = rne16(vb.z) | (rne16(vb.w) << 16);
      *(uint2*)&Bs[row * LDB + k4 * 4] = make_uint2(b0, b1);
    }
    __syncthreads();
#pragma unroll
    for (int kf = 0; kf < 2; kf++) {
      int ko = kf * 32 + (lane >> 4) * 8;
      short8 af[4], bf[4];
#pragma unroll
      for (int mi = 0; mi < 4; mi++)
        af[mi] = *(const short8*)&As[(wm * 64 + mi * 16 + (lane & 15)) * LDB + ko];
#pragma unroll
      for (int ni = 0; ni < 4; ni++)
        bf[ni] = *(const short8*)&Bs[(wn * 64 + ni * 16 + (lane & 15)) * LDB + ko];
#pragma unroll
      for (int mi = 0; mi < 4; mi++)
#pragma unroll
        for (int ni = 0; ni < 4; ni++)
          acc[mi][ni] = __builtin_amdgcn_mfma_f32_16x16x32_bf16(
              af[mi], bf[ni], acc[mi][ni], 0, 0, 0);
    }
  }

  int colbase = bn * BN + wn * 64 + (lane & 15);
  int rowbase = bm * BM + wm * 64 + (lane >> 4) * 4;
#pragma unroll
  for (int ni = 0; ni < 4; ni++) {
    int col = colbase + ni * 16;
    float be = b_enc[col];
#pragma unroll
    for (int mi = 0; mi < 4; mi++) {
#pragma unroll
      for (int r = 0; r < 4; r++) {
        int row = rowbase + mi * 16 + r;
        float v = acc[mi][ni][r] + be;
        z[(size_t)row * WIDTH + col] = v > 0.f ? v : 0.f;
      }
    }
  }
}

// ========= K2a: per-row top-64 set selection; sparsify z; emit (idx,val) list =========
__global__ __launch_bounds__(256) void sae_select(
    float* __restrict__ z, const float* __restrict__ x,
    const float* __restrict__ W, const float* __restrict__ b_enc,
    float* __restrict__ xhat)
{
  __shared__ u16    srow[WIDTH];      // 32768 B : bf16(s)
  __shared__ float  xrow[D_IN];       //  8192 B
  __shared__ u32    hist[256];
  __shared__ int    ci[CAP];          // candidate feature idx
  __shared__ float  cs[CAP];          // staged f32 value
  __shared__ int    ucand[CAP];       // uncertain -> candidate slot
  __shared__ double uval[CAP];        // exact value of uncertain
  __shared__ u32    wflag[CAP];       // winner flag per candidate
  __shared__ int    si[TOPK];
  __shared__ float  sv[TOPK];
  __shared__ int    ncand_s, nunc_s, m_s;
  __shared__ int    sel_hi_s;
  __shared__ u32    g1_s;
  __shared__ float  tp_s;

  const int tid = threadIdx.x;
  const int b   = blockIdx.x;
  float* zrow = z + (size_t)b * WIDTH;

  // one global pass: stage bf16(s) into LDS
  uint2* sr4 = (uint2*)srow;
  for (int i = tid; i < WIDTH / 4; i += 256) {
    float4 v = *(const float4*)(zrow + i * 4);
    sr4[i] = make_uint2(rne16(v.x) | (rne16(v.y) << 16),
                        rne16(v.z) | (rne16(v.w) << 16));
  }
  for (int i = tid; i < D_IN / 4; i += 256)
    *(float4*)&xrow[i * 4] = *(const float4*)(x + (size_t)b * D_IN + i * 4);
  if (tid == 0) { ncand_s = 0; nunc_s = 0; m_s = 0; }
  if (tid < TOPK) { si[tid] = 0; sv[tid] = 0.f; }
  hist[tid] = 0;
  __syncthreads();

  // 2-pass radix over bf16 bits (nonneg -> order-preserving) -> exact 64th of s'
  for (int j = tid; j < WIDTH; j += 256) atomicAdd(&hist[srow[j] >> 8], 1u);
  __syncthreads();
  if (tid == 0) {
    u32 cum = 0; int hi = 255;
    for (; hi > 0; hi--) { if (cum + hist[hi] >= TOPK) break; cum += hist[hi]; }
    sel_hi_s = hi; g1_s = cum;
  }
  __syncthreads();
  int sel_hi = sel_hi_s;
  hist[tid] = 0;
  __syncthreads();
  for (int j = tid; j < WIDTH; j += 256) {
    u16 k = srow[j];
    if ((int)(k >> 8) == sel_hi) atomicAdd(&hist[k & 255u], 1u);
  }
  __syncthreads();
  if (tid == 0) {
    u32 target = TOPK - g1_s;
    u32 cum = 0; int lo = 255;
    for (; lo > 0; lo--) { cum += hist[lo]; if (cum >= target) break; }
    tp_s = bf16f((u16)((sel_hi << 8) | lo));
  }
  __syncthreads();
  float tp = tp_s;

  // collect candidates from LDS
  float cLo = tp - COLL;
  for (int j = tid; j < WIDTH; j += 256) {
    if (bf16f(srow[j]) >= cLo) {
      int p = atomicAdd(&ncand_s, 1);
      if (p < CAP) ci[p] = j;
    }
  }
  __syncthreads();
  int nc = ncand_s; if (nc > CAP) nc = CAP;

  // fetch f32 staged values; classify sure-in / uncertain / out
  for (int c = tid; c < nc; c += 256) {
    float s = zrow[ci[c]];
    cs[c] = s;
    if (s > tp + SURE) { atomicAdd(&m_s, 1); wflag[c] = 1u; }
    else {
      wflag[c] = 0u;
      if (s >= tp - SURE) { int q = atomicAdd(&nunc_s, 1); ucand[q] = c; }
    }
  }
  __syncthreads();
  int m = m_s, nu = nunc_s;
  int k_rem = TOPK - m;

  // f64-exact recompute of uncertain only: one wave per candidate
  int wv = tid >> 6, lane = tid & 63;
  for (int q = wv; q < nu; q += 4) {
    int jc = ci[ucand[q]];
    const float4* wr = (const float4*)(W + (size_t)jc * D_IN);
    double s = 0.0;
    for (int it = 0; it < D_IN / 4 / 64; it++) {
      float4 w = wr[it * 64 + lane];
      int d = (it * 64 + lane) * 4;
      s += (double)xrow[d + 0] * (double)w.x;
      s += (double)xrow[d + 1] * (double)w.y;
      s += (double)xrow[d + 2] * (double)w.z;
      s += (double)xrow[d + 3] * (double)w.w;
    }
    for (int off = 32; off >= 1; off >>= 1) s += __shfl_down(s, off, 64);
    if (lane == 0) {
      double v = s + (double)b_enc[jc];
      uval[q] = v > 0.0 ? v : 0.0;      // relu (ref ranks relu'd z)
    }
  }
  __syncthreads();

  // rank uncertain (desc, lower index ties -> matches lax.top_k); take k_rem
  for (int q = tid; q < nu; q += 256) {
    double v = uval[q]; int jq = ci[ucand[q]];
    int rank = 0;
    for (int p = 0; p < nu; p++) {
      double vp = uval[p];
      if (vp > v || (vp == v && ci[ucand[p]] < jq)) rank++;
    }
    if (rank < k_rem) wflag[ucand[q]] = 1u;
  }
  __syncthreads();

  // deterministic slots: winners ordered by feature index
  for (int c = tid; c < nc; c += 256) {
    if (wflag[c]) {
      int jme = ci[c];
      int slot = 0;
      for (int p = 0; p < nc; p++) slot += (wflag[p] && ci[p] < jme) ? 1 : 0;
      si[slot] = jme;
      sv[slot] = cs[c];
    }
  }
  __syncthreads();

  // zero the z row, scatter the 64 winners (staged f32 values)
  for (int i = tid; i < WIDTH / 4; i += 256)
    *(float4*)(zrow + i * 4) = make_float4(0.f, 0.f, 0.f, 0.f);
  __syncthreads();
  if (tid < TOPK) zrow[si[tid]] = sv[tid];

  // stash compact list in the xhat row this block's decode will overwrite
  u32* lidx = (u32*)(xhat + (size_t)b * D_IN);
  if (tid < TOPK) {
    lidx[tid] = (u32)si[tid];
    ((float*)lidx)[TOPK + tid] = sv[tid];
  }
}

// ========= K2b: sparse decode; runs after all z streaming (W stays L3-hot) =========
__global__ __launch_bounds__(256) void sae_decode(
    const float* __restrict__ W, const float* __restrict__ b_dec,
    float* __restrict__ xhat)
{
  __shared__ int   si[TOPK];
  __shared__ float sv[TOPK];
  const int tid = threadIdx.x;
  const int b   = blockIdx.x;
  float* xo = xhat + (size_t)b * D_IN;

  if (tid < TOPK) {
    si[tid] = (int)((const u32*)xo)[tid];
    sv[tid] = xo[TOPK + tid];
  }
  __syncthreads();

  f32x4 a0 = {0.f, 0.f, 0.f, 0.f}, a1 = {0.f, 0.f, 0.f, 0.f};
  for (int k = 0; k < TOPK; k++) {
    int j = si[k]; float v = sv[k];
    const float4* wr = (const float4*)(W + (size_t)j * D_IN);
    float4 w0 = wr[tid];
    float4 w1 = wr[tid + 256];
    a0[0] = fmaf(v, w0.x, a0[0]); a0[1] = fmaf(v, w0.y, a0[1]);
    a0[2] = fmaf(v, w0.z, a0[2]); a0[3] = fmaf(v, w0.w, a0[3]);
    a1[0] = fmaf(v, w1.x, a1[0]); a1[1] = fmaf(v, w1.y, a1[1]);
    a1[2] = fmaf(v, w1.z, a1[2]); a1[3] = fmaf(v, w1.w, a1[3]);
  }
  float4 bd0 = ((const float4*)b_dec)[tid];
  float4 bd1 = ((const float4*)b_dec)[tid + 256];
  float4 o0 = make_float4(a0[0] + bd0.x, a0[1] + bd0.y, a0[2] + bd0.z, a0[3] + bd0.w);
  float4 o1 = make_float4(a1[0] + bd1.x, a1[1] + bd1.y, a1[2] + bd1.z, a1[3] + bd1.w);
  ((float4*)xo)[tid]       = o0;
  ((float4*)xo)[tid + 256] = o1;
}

// ------------------------------- launch -------------------------------
extern "C" void kernel_launch(void* const* d_in, const int* in_sizes, int n_in,
                              void* d_out, int out_size, void* d_ws, size_t ws_size,
                              hipStream_t stream) {
  const float* x     = (const float*)d_in[0];
  const float* W     = (const float*)d_in[1];
  const float* b_enc = (const float*)d_in[2];
  const float* b_dec = (const float*)d_in[3];
  (void)in_sizes; (void)n_in; (void)out_size; (void)d_ws; (void)ws_size;

  float* z_out = (float*)d_out;                      // [BATCH][WIDTH] f32
  float* xhat  = z_out + (size_t)BATCH * WIDTH;      // [BATCH][D_IN] f32

  dim3 g1(WIDTH / BN, BATCH / BM);
  sae_enc_mfma<<<g1, 256, 0, stream>>>(x, W, b_enc, z_out);
  sae_select<<<BATCH, 256, 0, stream>>>(z_out, x, W, b_enc, xhat);
  sae_decode<<<BATCH, 256, 0, stream>>>(W, b_dec, xhat);
}

// Round 10
// 2214.487 us; speedup vs baseline: 17.1495x; 1.2440x over previous
//
#include <hip/hip_runtime.h>

#define D_IN   2048
#define WIDTH  16384
#define BATCH  8192
#define TOPK   64

// ---- K1 (MFMA GEMM, m97 structure) ----
#define BM  128
#define BN  128
#define BK  64

// ---- K2a (select) ----
#define CAP   256
#define COLL  0.022f      // collect band on bf16-staged s'
#define SURE  0.018f      // certainty band on f32-staged s

typedef unsigned int   u32;
typedef unsigned short u16;
typedef __attribute__((ext_vector_type(8))) short short8;
typedef __attribute__((ext_vector_type(4))) float f32x4;

__device__ __forceinline__ u32 rne16(float f) {           // f32 -> bf16 bits (RNE)
  u32 u = __float_as_uint(f);
  return (u + 0x7FFFu + ((u >> 16) & 1u)) >> 16;
}
__device__ __forceinline__ float bf16f(u16 h) {
  return __uint_as_float(((u32)h) << 16);
}
__device__ __forceinline__ void gload_lds16(const void* g, void* l) {
  __builtin_amdgcn_global_load_lds(
      (__attribute__((address_space(1))) void*)g,
      (__attribute__((address_space(3))) void*)l, 16, 0, 0);
}

// =============== P0: f32 -> bf16 (RNE) bulk convert into workspace ===============
__global__ __launch_bounds__(256) void cvt_bf16_k(
    const float* __restrict__ in, u16* __restrict__ out, int n4)
{
  int stride = gridDim.x * 256;
  for (int i = blockIdx.x * 256 + threadIdx.x; i < n4; i += stride) {
    float4 v = ((const float4*)in)[i];
    ((uint2*)out)[i] = make_uint2(rne16(v.x) | (rne16(v.y) << 16),
                                  rne16(v.z) | (rne16(v.w) << 16));
  }
}

// ====== K1: z = relu(x @ W^T + b_enc), bf16 MFMA, global_load_lds staging ======
__global__ __launch_bounds__(256) void sae_enc_mfma2(
    const u16* __restrict__ xbf, const u16* __restrict__ wbf,
    const float* __restrict__ b_enc, float* __restrict__ z)
{
  __shared__ u16 As[BM * BK];      // linear [row][k], 16384 B
  __shared__ u16 Bs[BN * BK];      // linear [row][k], 16384 B

  const int tid  = threadIdx.x;
  const int lane = tid & 63;
  const int w    = tid >> 6;
  const int wm   = w >> 1;
  const int wn   = w & 1;
  const int bn   = blockIdx.x;
  const int bm   = blockIdx.y;

  f32x4 acc[4][4];
#pragma unroll
  for (int i = 0; i < 4; i++)
#pragma unroll
    for (int j = 0; j < 4; j++) acc[i][j] = (f32x4){0.f, 0.f, 0.f, 0.f};

  const u16* ag = xbf + (size_t)(bm * BM) * D_IN;
  const u16* bg = wbf + (size_t)(bn * BN) * D_IN;

  const int rL = lane >> 3;            // 0..7 row within 8-row chunk
  const int kq = (lane & 7) * 8;       // bf16 k offset (16B granule)

  for (int k0 = 0; k0 < D_IN; k0 += BK) {
    __syncthreads();                   // previous compute done before overwrite
    // stage A and B: each wave issues 4+4 global_load_lds_dwordx4 (1 KB each)
#pragma unroll
    for (int c = 0; c < 4; c++) {
      int r0 = (w * 4 + c) * 8;
      gload_lds16(ag + (size_t)(r0 + rL) * D_IN + k0 + kq, &As[r0 * BK]);
    }
#pragma unroll
    for (int c = 0; c < 4; c++) {
      int r0 = (w * 4 + c) * 8;
      gload_lds16(bg + (size_t)(r0 + rL) * D_IN + k0 + kq, &Bs[r0 * BK]);
    }
    __syncthreads();                   // drains vmcnt(0): tiles resident
#pragma unroll
    for (int kf = 0; kf < 2; kf++) {
      int ko = kf * 32 + (lane >> 4) * 8;
      short8 af[4], bf[4];
#pragma unroll
      for (int mi = 0; mi < 4; mi++)
        af[mi] = *(const short8*)&As[(wm * 64 + mi * 16 + (lane & 15)) * BK + ko];
#pragma unroll
      for (int ni = 0; ni < 4; ni++)
        bf[ni] = *(const short8*)&Bs[(wn * 64 + ni * 16 + (lane & 15)) * BK + ko];
#pragma unroll
      for (int mi = 0; mi < 4; mi++)
#pragma unroll
        for (int ni = 0; ni < 4; ni++)
          acc[mi][ni] = __builtin_amdgcn_mfma_f32_16x16x32_bf16(
              af[mi], bf[ni], acc[mi][ni], 0, 0, 0);
    }
  }

  // epilogue: C layout col = lane&15, row = (lane>>4)*4 + reg
  int colbase = bn * BN + wn * 64 + (lane & 15);
  int rowbase = bm * BM + wm * 64 + (lane >> 4) * 4;
#pragma unroll
  for (int ni = 0; ni < 4; ni++) {
    int col = colbase + ni * 16;
    float be = b_enc[col];
#pragma unroll
    for (int mi = 0; mi < 4; mi++) {
#pragma unroll
      for (int r = 0; r < 4; r++) {
        int row = rowbase + mi * 16 + r;
        float v = acc[mi][ni][r] + be;
        z[(size_t)row * WIDTH + col] = v > 0.f ? v : 0.f;
      }
    }
  }
}

// ========= K2a: per-row top-64 set selection (register-resident row) =========
__global__ __launch_bounds__(256) void sae_select2(
    float* __restrict__ z, const float* __restrict__ x,
    const float* __restrict__ W, const float* __restrict__ b_enc,
    float* __restrict__ xhat)
{
  __shared__ float  xrow[D_IN];       // 8192 B
  __shared__ u32    hist[256];
  __shared__ int    ci[CAP];
  __shared__ float  cs[CAP];
  __shared__ int    ucand[CAP];
  __shared__ double uval[CAP];
  __shared__ u32    wflag[CAP];
  __shared__ int    si[TOPK];
  __shared__ float  sv[TOPK];
  __shared__ int    ncand_s, nunc_s, m_s, sel_hi_s;
  __shared__ u32    g1_s;
  __shared__ float  tp_s;

  const int tid = threadIdx.x;
  const int b   = blockIdx.x;
  float* zrow = z + (size_t)b * WIDTH;
  const float4* zr4 = (const float4*)zrow;

  for (int i = tid; i < D_IN / 4; i += 256)
    ((float4*)xrow)[i] = ((const float4*)(x + (size_t)b * D_IN))[i];
  if (tid == 0) { ncand_s = 0; nunc_s = 0; m_s = 0; }
  if (tid < TOPK) { si[tid] = 0; sv[tid] = 0.f; }
  hist[tid] = 0;
  __syncthreads();

  // one z read: row lives in 32 packed-bf16 registers per thread
  u32 pk[32];
#pragma unroll
  for (int i = 0; i < 16; i++) {
    float4 v = zr4[i * 256 + tid];
    pk[2 * i]     = rne16(v.x) | (rne16(v.y) << 16);
    pk[2 * i + 1] = rne16(v.z) | (rne16(v.w) << 16);
  }

  // radix pass 1 on bf16 bits (nonneg -> order-preserving): bits[15:8]
#pragma unroll
  for (int i = 0; i < 32; i++) {
    u32 p = pk[i];
    atomicAdd(&hist[(p >> 8) & 255u], 1u);
    atomicAdd(&hist[p >> 24], 1u);
  }
  __syncthreads();
  if (tid == 0) {
    u32 cum = 0; int hi = 255;
    for (; hi > 0; hi--) { if (cum + hist[hi] >= TOPK) break; cum += hist[hi]; }
    sel_hi_s = hi; g1_s = cum;
  }
  __syncthreads();
  int sel_hi = sel_hi_s;
  hist[tid] = 0;
  __syncthreads();
  // radix pass 2: bits[7:0] within boundary high-bin
#pragma unroll
  for (int i = 0; i < 32; i++) {
    u32 p = pk[i];
    if ((int)((p >> 8) & 255u) == sel_hi) atomicAdd(&hist[p & 255u], 1u);
    if ((int)(p >> 24) == sel_hi) atomicAdd(&hist[(p >> 16) & 255u], 1u);
  }
  __syncthreads();
  if (tid == 0) {
    u32 target = TOPK - g1_s;
    u32 cum = 0; int lo = 255;
    for (; lo > 0; lo--) { cum += hist[lo]; if (cum >= target) break; }
    tp_s = bf16f((u16)((sel_hi << 8) | lo));
  }
  __syncthreads();
  float tp = tp_s;
  float cLo = tp - COLL;

  // collect candidates from registers
#pragma unroll
  for (int i = 0; i < 16; i++) {
    u32 p0 = pk[2 * i], p1 = pk[2 * i + 1];
    int j0 = (i * 256 + tid) * 4;
    if (bf16f((u16)p0) >= cLo)         { int p = atomicAdd(&ncand_s, 1); if (p < CAP) ci[p] = j0; }
    if (bf16f((u16)(p0 >> 16)) >= cLo) { int p = atomicAdd(&ncand_s, 1); if (p < CAP) ci[p] = j0 + 1; }
    if (bf16f((u16)p1) >= cLo)         { int p = atomicAdd(&ncand_s, 1); if (p < CAP) ci[p] = j0 + 2; }
    if (bf16f((u16)(p1 >> 16)) >= cLo) { int p = atomicAdd(&ncand_s, 1); if (p < CAP) ci[p] = j0 + 3; }
  }
  __syncthreads();
  int nc = ncand_s; if (nc > CAP) nc = CAP;

  // classify with the f32 staged value: sure-in / uncertain / out
  for (int c = tid; c < nc; c += 256) {
    float s = zrow[ci[c]];
    cs[c] = s;
    if (s > tp + SURE) { atomicAdd(&m_s, 1); wflag[c] = 1u; }
    else {
      wflag[c] = 0u;
      if (s >= tp - SURE) { int q = atomicAdd(&nunc_s, 1); ucand[q] = c; }
    }
  }
  __syncthreads();
  int m = m_s, nu = nunc_s;
  int k_rem = TOPK - m;

  // f64-exact recompute of uncertain only: one wave per candidate
  int wv = tid >> 6, lane = tid & 63;
  for (int q = wv; q < nu; q += 4) {
    int jc = ci[ucand[q]];
    const float4* wr = (const float4*)(W + (size_t)jc * D_IN);
    double s = 0.0;
    for (int it = 0; it < D_IN / 4 / 64; it++) {
      float4 w = wr[it * 64 + lane];
      int d = (it * 64 + lane) * 4;
      s += (double)xrow[d + 0] * (double)w.x;
      s += (double)xrow[d + 1] * (double)w.y;
      s += (double)xrow[d + 2] * (double)w.z;
      s += (double)xrow[d + 3] * (double)w.w;
    }
    for (int off = 32; off >= 1; off >>= 1) s += __shfl_down(s, off, 64);
    if (lane == 0) {
      double v = s + (double)b_enc[jc];
      uval[q] = v > 0.0 ? v : 0.0;
    }
  }
  __syncthreads();

  // rank uncertain (desc, lower index ties -> matches lax.top_k); take k_rem
  for (int q = tid; q < nu; q += 256) {
    double v = uval[q]; int jq = ci[ucand[q]];
    int rank = 0;
    for (int p = 0; p < nu; p++) {
      double vp = uval[p];
      if (vp > v || (vp == v && ci[ucand[p]] < jq)) rank++;
    }
    if (rank < k_rem) wflag[ucand[q]] = 1u;
  }
  __syncthreads();

  // deterministic slots: winners ordered by feature index
  for (int c = tid; c < nc; c += 256) {
    if (wflag[c]) {
      int jme = ci[c];
      int slot = 0;
      for (int p = 0; p < nc; p++) slot += (wflag[p] && ci[p] < jme) ? 1 : 0;
      si[slot] = jme;
      sv[slot] = cs[c];
    }
  }
  __syncthreads();

  // zero the z row, scatter the 64 winners (staged f32 values)
  for (int i = tid; i < WIDTH / 4; i += 256)
    *(float4*)(zrow + i * 4) = make_float4(0.f, 0.f, 0.f, 0.f);
  __syncthreads();
  if (tid < TOPK) zrow[si[tid]] = sv[tid];

  // stash compact list in the xhat row this block's decode will overwrite
  u32* lidx = (u32*)(xhat + (size_t)b * D_IN);
  if (tid < TOPK) {
    lidx[tid] = (u32)si[tid];
    ((float*)lidx)[TOPK + tid] = sv[tid];
  }
}

// ========= K2b: sparse decode; runs after all z streaming (W stays L3-hot) =========
__global__ __launch_bounds__(256) void sae_decode(
    const float* __restrict__ W, const float* __restrict__ b_dec,
    float* __restrict__ xhat)
{
  __shared__ int   si[TOPK];
  __shared__ float sv[TOPK];
  const int tid = threadIdx.x;
  const int b   = blockIdx.x;
  float* xo = xhat + (size_t)b * D_IN;

  if (tid < TOPK) {
    si[tid] = (int)((const u32*)xo)[tid];
    sv[tid] = xo[TOPK + tid];
  }
  __syncthreads();

  f32x4 a0 = {0.f, 0.f, 0.f, 0.f}, a1 = {0.f, 0.f, 0.f, 0.f};
  for (int k = 0; k < TOPK; k++) {
    int j = si[k]; float v = sv[k];
    const float4* wr = (const float4*)(W + (size_t)j * D_IN);
    float4 w0 = wr[tid];
    float4 w1 = wr[tid + 256];
    a0[0] = fmaf(v, w0.x, a0[0]); a0[1] = fmaf(v, w0.y, a0[1]);
    a0[2] = fmaf(v, w0.z, a0[2]); a0[3] = fmaf(v, w0.w, a0[3]);
    a1[0] = fmaf(v, w1.x, a1[0]); a1[1] = fmaf(v, w1.y, a1[1]);
    a1[2] = fmaf(v, w1.z, a1[2]); a1[3] = fmaf(v, w1.w, a1[3]);
  }
  float4 bd0 = ((const float4*)b_dec)[tid];
  float4 bd1 = ((const float4*)b_dec)[tid + 256];
  ((float4*)xo)[tid]       = make_float4(a0[0] + bd0.x, a0[1] + bd0.y, a0[2] + bd0.z, a0[3] + bd0.w);
  ((float4*)xo)[tid + 256] = make_float4(a1[0] + bd1.x, a1[1] + bd1.y, a1[2] + bd1.z, a1[3] + bd1.w);
}

// ------------------------------- launch -------------------------------
extern "C" void kernel_launch(void* const* d_in, const int* in_sizes, int n_in,
                              void* d_out, int out_size, void* d_ws, size_t ws_size,
                              hipStream_t stream) {
  const float* x     = (const float*)d_in[0];
  const float* W     = (const float*)d_in[1];
  const float* b_enc = (const float*)d_in[2];
  const float* b_dec = (const float*)d_in[3];
  (void)in_sizes; (void)n_in; (void)out_size; (void)ws_size;

  float* z_out = (float*)d_out;                      // [BATCH][WIDTH] f32
  float* xhat  = z_out + (size_t)BATCH * WIDTH;      // [BATCH][D_IN] f32

  u16* xbf = (u16*)d_ws;                             // 33.5 MB
  u16* wbf = xbf + (size_t)BATCH * D_IN;             // 67.1 MB (total ~100.6 MB < proven ws)

  cvt_bf16_k<<<2048, 256, 0, stream>>>(x, xbf, BATCH * D_IN / 4);
  cvt_bf16_k<<<2048, 256, 0, stream>>>(W, wbf, WIDTH * D_IN / 4);

  dim3 g1(WIDTH / BN, BATCH / BM);                   // 128 x 64
  sae_enc_mfma2<<<g1, 256, 0, stream>>>(xbf, wbf, b_enc, z_out);
  sae_select2<<<BATCH, 256, 0, stream>>>(z_out, x, W, b_enc, xhat);
  sae_decode<<<BATCH, 256, 0, stream>>>(W, b_dec, xhat);
}

// Round 11
// 1835.639 us; speedup vs baseline: 20.6889x; 1.2064x over previous
//
#include <hip/hip_runtime.h>

#define D_IN   2048
#define WIDTH  16384
#define BATCH  8192
#define TOPK   64

// ---- K1 (MFMA GEMM, m97 structure + T2 swizzle) ----
#define BM  128
#define BN  128
#define BK  64

// ---- K2a (select) ----
#define CAP   256
#define COLL  0.022f      // collect band on bf16-staged s'
#define SURE  0.018f      // certainty band on f32-staged s

typedef unsigned int   u32;
typedef unsigned short u16;
typedef __attribute__((ext_vector_type(8))) short short8;
typedef __attribute__((ext_vector_type(4))) float f32x4;

__device__ __forceinline__ u32 rne16(float f) {           // f32 -> bf16 bits (RNE)
  u32 u = __float_as_uint(f);
  return (u + 0x7FFFu + ((u >> 16) & 1u)) >> 16;
}
__device__ __forceinline__ float bf16f(u16 h) {
  return __uint_as_float(((u32)h) << 16);
}
__device__ __forceinline__ void gload_lds16(const void* g, void* l) {
  __builtin_amdgcn_global_load_lds(
      (__attribute__((address_space(1))) void*)g,
      (__attribute__((address_space(3))) void*)l, 16, 0, 0);
}

// =============== P0: f32 -> bf16 (RNE) bulk convert into workspace ===============
__global__ __launch_bounds__(256) void cvt_bf16_k(
    const float* __restrict__ in, u16* __restrict__ out, int n4)
{
  int stride = gridDim.x * 256;
  for (int i = blockIdx.x * 256 + threadIdx.x; i < n4; i += stride) {
    float4 v = ((const float4*)in)[i];
    ((uint2*)out)[i] = make_uint2(rne16(v.x) | (rne16(v.y) << 16),
                                  rne16(v.z) | (rne16(v.w) << 16));
  }
}

// ====== K1: z = relu(x @ W^T + b_enc), bf16 MFMA, gload_lds + XOR swizzle ======
// Swizzle invariant (rule #21, both sides, same involution on 16B granules):
//   LDS[row][bo] holds global k-byte (bo ^ ((row&7)<<4)); staging achieves this by
//   per-lane pre-swizzled global source; reads apply ko ^= (row&7)<<3 (elems).
__global__ __launch_bounds__(256) void sae_enc_mfma3(
    const u16* __restrict__ xbf, const u16* __restrict__ wbf,
    const float* __restrict__ b_enc, float* __restrict__ z)
{
  __shared__ u16 As[BM * BK];      // 16384 B
  __shared__ u16 Bs[BN * BK];      // 16384 B

  const int tid  = threadIdx.x;
  const int lane = tid & 63;
  const int w    = tid >> 6;
  const int wm   = w >> 1;
  const int wn   = w & 1;

  // XCD-aware bijective block swizzle (8192 blocks, 8 XCDs, 1024 per XCD)
  const int orig = blockIdx.x;
  const int swz  = (orig & 7) * 1024 + (orig >> 3);
  const int bm   = swz >> 7;       // 0..63
  const int bn   = swz & 127;      // 0..127

  f32x4 acc[4][4];
#pragma unroll
  for (int i = 0; i < 4; i++)
#pragma unroll
    for (int j = 0; j < 4; j++) acc[i][j] = (f32x4){0.f, 0.f, 0.f, 0.f};

  const u16* ag = xbf + (size_t)(bm * BM) * D_IN;
  const u16* bg = wbf + (size_t)(bn * BN) * D_IN;

  const int rL    = lane >> 3;                          // row within 8-row chunk
  const int kq_sw = ((lane & 7) ^ (lane >> 3)) * 8;     // pre-swizzled k offset (elems)

  for (int k0 = 0; k0 < D_IN; k0 += BK) {
    __syncthreads();
#pragma unroll
    for (int c = 0; c < 4; c++) {
      int r0 = (w * 4 + c) * 8;
      gload_lds16(ag + (size_t)(r0 + rL) * D_IN + k0 + kq_sw, &As[r0 * BK]);
    }
#pragma unroll
    for (int c = 0; c < 4; c++) {
      int r0 = (w * 4 + c) * 8;
      gload_lds16(bg + (size_t)(r0 + rL) * D_IN + k0 + kq_sw, &Bs[r0 * BK]);
    }
    __syncthreads();
#pragma unroll
    for (int kf = 0; kf < 2; kf++) {
      int ko = kf * 32 + (lane >> 4) * 8;
      short8 af[4], bf[4];
#pragma unroll
      for (int mi = 0; mi < 4; mi++) {
        int row = wm * 64 + mi * 16 + (lane & 15);
        af[mi] = *(const short8*)&As[row * BK + (ko ^ ((row & 7) << 3))];
      }
#pragma unroll
      for (int ni = 0; ni < 4; ni++) {
        int row = wn * 64 + ni * 16 + (lane & 15);
        bf[ni] = *(const short8*)&Bs[row * BK + (ko ^ ((row & 7) << 3))];
      }
#pragma unroll
      for (int mi = 0; mi < 4; mi++)
#pragma unroll
        for (int ni = 0; ni < 4; ni++)
          acc[mi][ni] = __builtin_amdgcn_mfma_f32_16x16x32_bf16(
              af[mi], bf[ni], acc[mi][ni], 0, 0, 0);
    }
  }

  // epilogue: C layout col = lane&15, row = (lane>>4)*4 + reg
  int colbase = bn * BN + wn * 64 + (lane & 15);
  int rowbase = bm * BM + wm * 64 + (lane >> 4) * 4;
#pragma unroll
  for (int ni = 0; ni < 4; ni++) {
    int col = colbase + ni * 16;
    float be = b_enc[col];
#pragma unroll
    for (int mi = 0; mi < 4; mi++) {
#pragma unroll
      for (int r = 0; r < 4; r++) {
        int row = rowbase + mi * 16 + r;
        float v = acc[mi][ni][r] + be;
        z[(size_t)row * WIDTH + col] = v > 0.f ? v : 0.f;
      }
    }
  }
}

// ========= K2a: per-row top-64 set selection (register-resident row) =========
__global__ __launch_bounds__(256) void sae_select2(
    float* __restrict__ z, const float* __restrict__ x,
    const float* __restrict__ W, const float* __restrict__ b_enc,
    float* __restrict__ xhat)
{
  __shared__ float  xrow[D_IN];
  __shared__ u32    hist[256];
  __shared__ int    ci[CAP];
  __shared__ float  cs[CAP];
  __shared__ int    ucand[CAP];
  __shared__ double uval[CAP];
  __shared__ u32    wflag[CAP];
  __shared__ int    si[TOPK];
  __shared__ float  sv[TOPK];
  __shared__ int    ncand_s, nunc_s, m_s, sel_hi_s;
  __shared__ u32    g1_s;
  __shared__ float  tp_s;

  const int tid = threadIdx.x;
  const int b   = blockIdx.x;
  float* zrow = z + (size_t)b * WIDTH;
  const float4* zr4 = (const float4*)zrow;

  for (int i = tid; i < D_IN / 4; i += 256)
    ((float4*)xrow)[i] = ((const float4*)(x + (size_t)b * D_IN))[i];
  if (tid == 0) { ncand_s = 0; nunc_s = 0; m_s = 0; }
  if (tid < TOPK) { si[tid] = 0; sv[tid] = 0.f; }
  hist[tid] = 0;
  __syncthreads();

  // one z read: row lives in 32 packed-bf16 registers per thread
  u32 pk[32];
#pragma unroll
  for (int i = 0; i < 16; i++) {
    float4 v = zr4[i * 256 + tid];
    pk[2 * i]     = rne16(v.x) | (rne16(v.y) << 16);
    pk[2 * i + 1] = rne16(v.z) | (rne16(v.w) << 16);
  }

  // radix pass 1 on bf16 bits (nonneg -> order-preserving)
#pragma unroll
  for (int i = 0; i < 32; i++) {
    u32 p = pk[i];
    atomicAdd(&hist[(p >> 8) & 255u], 1u);
    atomicAdd(&hist[p >> 24], 1u);
  }
  __syncthreads();
  if (tid == 0) {
    u32 cum = 0; int hi = 255;
    for (; hi > 0; hi--) { if (cum + hist[hi] >= TOPK) break; cum += hist[hi]; }
    sel_hi_s = hi; g1_s = cum;
  }
  __syncthreads();
  int sel_hi = sel_hi_s;
  hist[tid] = 0;
  __syncthreads();
#pragma unroll
  for (int i = 0; i < 32; i++) {
    u32 p = pk[i];
    if ((int)((p >> 8) & 255u) == sel_hi) atomicAdd(&hist[p & 255u], 1u);
    if ((int)(p >> 24) == sel_hi) atomicAdd(&hist[(p >> 16) & 255u], 1u);
  }
  __syncthreads();
  if (tid == 0) {
    u32 target = TOPK - g1_s;
    u32 cum = 0; int lo = 255;
    for (; lo > 0; lo--) { cum += hist[lo]; if (cum >= target) break; }
    tp_s = bf16f((u16)((sel_hi << 8) | lo));
  }
  __syncthreads();
  float tp = tp_s;
  float cLo = tp - COLL;

  // collect candidates from registers
#pragma unroll
  for (int i = 0; i < 16; i++) {
    u32 p0 = pk[2 * i], p1 = pk[2 * i + 1];
    int j0 = (i * 256 + tid) * 4;
    if (bf16f((u16)p0) >= cLo)         { int p = atomicAdd(&ncand_s, 1); if (p < CAP) ci[p] = j0; }
    if (bf16f((u16)(p0 >> 16)) >= cLo) { int p = atomicAdd(&ncand_s, 1); if (p < CAP) ci[p] = j0 + 1; }
    if (bf16f((u16)p1) >= cLo)         { int p = atomicAdd(&ncand_s, 1); if (p < CAP) ci[p] = j0 + 2; }
    if (bf16f((u16)(p1 >> 16)) >= cLo) { int p = atomicAdd(&ncand_s, 1); if (p < CAP) ci[p] = j0 + 3; }
  }
  __syncthreads();
  int nc = ncand_s; if (nc > CAP) nc = CAP;

  // classify with the f32 staged value: sure-in / uncertain / out
  for (int c = tid; c < nc; c += 256) {
    float s = zrow[ci[c]];
    cs[c] = s;
    if (s > tp + SURE) { atomicAdd(&m_s, 1); wflag[c] = 1u; }
    else {
      wflag[c] = 0u;
      if (s >= tp - SURE) { int q = atomicAdd(&nunc_s, 1); ucand[q] = c; }
    }
  }
  __syncthreads();
  int m = m_s, nu = nunc_s;
  int k_rem = TOPK - m;

  // f64-exact recompute of uncertain only (f32 W: matches np reference exactly)
  int wv = tid >> 6, lane = tid & 63;
  for (int q = wv; q < nu; q += 4) {
    int jc = ci[ucand[q]];
    const float4* wr = (const float4*)(W + (size_t)jc * D_IN);
    double s = 0.0;
    for (int it = 0; it < D_IN / 4 / 64; it++) {
      float4 wd = wr[it * 64 + lane];
      int d = (it * 64 + lane) * 4;
      s += (double)xrow[d + 0] * (double)wd.x;
      s += (double)xrow[d + 1] * (double)wd.y;
      s += (double)xrow[d + 2] * (double)wd.z;
      s += (double)xrow[d + 3] * (double)wd.w;
    }
    for (int off = 32; off >= 1; off >>= 1) s += __shfl_down(s, off, 64);
    if (lane == 0) {
      double v = s + (double)b_enc[jc];
      uval[q] = v > 0.0 ? v : 0.0;
    }
  }
  __syncthreads();

  // rank uncertain (desc, lower index ties -> matches lax.top_k); take k_rem
  for (int q = tid; q < nu; q += 256) {
    double v = uval[q]; int jq = ci[ucand[q]];
    int rank = 0;
    for (int p = 0; p < nu; p++) {
      double vp = uval[p];
      if (vp > v || (vp == v && ci[ucand[p]] < jq)) rank++;
    }
    if (rank < k_rem) wflag[ucand[q]] = 1u;
  }
  __syncthreads();

  // deterministic slots: winners ordered by feature index
  for (int c = tid; c < nc; c += 256) {
    if (wflag[c]) {
      int jme = ci[c];
      int slot = 0;
      for (int p = 0; p < nc; p++) slot += (wflag[p] && ci[p] < jme) ? 1 : 0;
      si[slot] = jme;
      sv[slot] = cs[c];
    }
  }
  __syncthreads();

  // zero the z row, scatter the 64 winners (staged f32 values)
  for (int i = tid; i < WIDTH / 4; i += 256)
    *(float4*)(zrow + i * 4) = make_float4(0.f, 0.f, 0.f, 0.f);
  __syncthreads();
  if (tid < TOPK) zrow[si[tid]] = sv[tid];

  // stash compact list in the xhat row this block's decode will overwrite
  u32* lidx = (u32*)(xhat + (size_t)b * D_IN);
  if (tid < TOPK) {
    lidx[tid] = (u32)si[tid];
    ((float*)lidx)[TOPK + tid] = sv[tid];
  }
}

// ========= K2b: sparse decode from bf16 W (half traffic, cache-hot) =========
__global__ __launch_bounds__(256) void sae_decode2(
    const u16* __restrict__ wbf, const float* __restrict__ b_dec,
    float* __restrict__ xhat)
{
  __shared__ int   si[TOPK];
  __shared__ float sv[TOPK];
  const int tid = threadIdx.x;
  const int b   = blockIdx.x;
  float* xo = xhat + (size_t)b * D_IN;

  if (tid < TOPK) {
    si[tid] = (int)((const u32*)xo)[tid];
    sv[tid] = xo[TOPK + tid];
  }
  __syncthreads();

  float a[8];
#pragma unroll
  for (int u = 0; u < 8; u++) a[u] = 0.f;
  for (int k = 0; k < TOPK; k++) {
    int j = si[k]; float v = sv[k];
    uint4 wv = *(const uint4*)(wbf + (size_t)j * D_IN + tid * 8);   // 8 bf16, coalesced
    a[0] = fmaf(v, __uint_as_float(wv.x << 16),        a[0]);
    a[1] = fmaf(v, __uint_as_float(wv.x & 0xFFFF0000u), a[1]);
    a[2] = fmaf(v, __uint_as_float(wv.y << 16),        a[2]);
    a[3] = fmaf(v, __uint_as_float(wv.y & 0xFFFF0000u), a[3]);
    a[4] = fmaf(v, __uint_as_float(wv.z << 16),        a[4]);
    a[5] = fmaf(v, __uint_as_float(wv.z & 0xFFFF0000u), a[5]);
    a[6] = fmaf(v, __uint_as_float(wv.w << 16),        a[6]);
    a[7] = fmaf(v, __uint_as_float(wv.w & 0xFFFF0000u), a[7]);
  }
  int d0 = tid * 8;
  float4 bd0 = *(const float4*)(b_dec + d0);
  float4 bd1 = *(const float4*)(b_dec + d0 + 4);
  __syncthreads();   // stash reads done before overwrite
  *(float4*)(xo + d0)     = make_float4(a[0] + bd0.x, a[1] + bd0.y, a[2] + bd0.z, a[3] + bd0.w);
  *(float4*)(xo + d0 + 4) = make_float4(a[4] + bd1.x, a[5] + bd1.y, a[6] + bd1.z, a[7] + bd1.w);
}

// ------------------------------- launch -------------------------------
extern "C" void kernel_launch(void* const* d_in, const int* in_sizes, int n_in,
                              void* d_out, int out_size, void* d_ws, size_t ws_size,
                              hipStream_t stream) {
  const float* x     = (const float*)d_in[0];
  const float* W     = (const float*)d_in[1];
  const float* b_enc = (const float*)d_in[2];
  const float* b_dec = (const float*)d_in[3];
  (void)in_sizes; (void)n_in; (void)out_size; (void)ws_size;

  float* z_out = (float*)d_out;                      // [BATCH][WIDTH] f32
  float* xhat  = z_out + (size_t)BATCH * WIDTH;      // [BATCH][D_IN] f32

  u16* xbf = (u16*)d_ws;                             // 33.5 MB
  u16* wbf = xbf + (size_t)BATCH * D_IN;             // 67.1 MB

  cvt_bf16_k<<<2048, 256, 0, stream>>>(x, xbf, BATCH * D_IN / 4);
  cvt_bf16_k<<<2048, 256, 0, stream>>>(W, wbf, WIDTH * D_IN / 4);

  sae_enc_mfma3<<<8192, 256, 0, stream>>>(xbf, wbf, b_enc, z_out);
  sae_select2<<<BATCH, 256, 0, stream>>>(z_out, x, W, b_enc, xhat);
  sae_decode2<<<BATCH, 256, 0, stream>>>(wbf, b_dec, xhat);
}